// Round 1
// baseline (117.749 us; speedup 1.0000x reference)
//
#include <hip/hip_runtime.h>

// PixelShift: out[c,d,i,j] = x[c,d,(i - s0[d]) mod H, (j - s1[d]) mod W]
// C=4, D=16, H=W=1024, float32. Pure memory-bound circular roll per depth slice.

#define CC 4
#define DD 16
#define HH 1024
#define WW 1024

__global__ void PixelShift_kernel(const float* __restrict__ x,
                                  const int* __restrict__ shift,
                                  float* __restrict__ out) {
    // Process in float4 units on the output side (aligned, coalesced stores).
    const int total4 = CC * DD * HH * (WW / 4);           // 16,777,216
    const int stride = gridDim.x * blockDim.x;
    for (int t = blockIdx.x * blockDim.x + threadIdx.x; t < total4; t += stride) {
        // Decompose: t = ((cd * H + i) * (W/4) + j4), all power-of-two -> shifts
        const int j4 = t & (WW / 4 - 1);                  // 0..255
        const int r  = t >> 8;                            // cd*H + i
        const int i  = r & (HH - 1);
        const int cd = r >> 10;                           // c*D + d
        const int d  = cd & (DD - 1);

        const int s0 = shift[2 * d];
        const int s1 = shift[2 * d + 1];

        // Two's-complement AND == proper mod for power-of-two, handles negatives.
        const int si = (i - s0) & (HH - 1);
        const float* __restrict__ src_row = x + ((long long)(cd & ~(DD - 1) ? cd : cd) * HH + 0); // placeholder avoided below
        const float* __restrict__ row = x + (((long long)cd * HH) + si) * WW;

        const int jb = (j4 << 2) - s1;
        float4 v;
        v.x = row[(jb    ) & (WW - 1)];
        v.y = row[(jb + 1) & (WW - 1)];
        v.z = row[(jb + 2) & (WW - 1)];
        v.w = row[(jb + 3) & (WW - 1)];

        reinterpret_cast<float4*>(out)[t] = v;
    }
}

extern "C" void kernel_launch(void* const* d_in, const int* in_sizes, int n_in,
                              void* d_out, int out_size, void* d_ws, size_t ws_size,
                              hipStream_t stream) {
    const float* x     = (const float*)d_in[0];
    const int*   shift = (const int*)d_in[1];
    float*       out   = (float*)d_out;

    const int blocks = 2048;   // 256 CUs x 8 blocks, grid-stride covers the rest
    const int threads = 256;
    PixelShift_kernel<<<blocks, threads, 0, stream>>>(x, shift, out);
}

// Round 2
// 106.505 us; speedup vs baseline: 1.1056x; 1.1056x over previous
//
#include <hip/hip_runtime.h>

// PixelShift: out[c,d,i,j] = x[c,d,(i - s0[d]) & 1023, (j - s1[d]) & 1023]
// C=4, D=16, H=W=1024, float32. Memory-bound circular roll per depth slice.
//
// Strategy: aligned float4 stores; reads are a contiguous (but element-
// misaligned) 16B load in the common case, with a rare masked scalar path
// only when the 4-element span crosses the row wrap (<=3 of 1024 positions).

#define CC 4
#define DD 16
#define HH 1024
#define WW 1024

// 4-byte-aligned 16B chunk: lets the compiler emit global_load_dwordx4
// (gfx950 supports element-misaligned vector access) without UB on alignment.
struct __align__(4) f4u { float x, y, z, w; };

__global__ __launch_bounds__(256)
void PixelShift_kernel(const float* __restrict__ x,
                       const int* __restrict__ shift,
                       float* __restrict__ out) {
    __shared__ int s_sh[2 * DD];
    if (threadIdx.x < 2 * DD) s_sh[threadIdx.x] = shift[threadIdx.x];
    __syncthreads();

    const int total4 = CC * DD * HH * (WW / 4);           // 16,777,216 float4s
    const int stride = gridDim.x * blockDim.x;
    for (int t = blockIdx.x * blockDim.x + threadIdx.x; t < total4; t += stride) {
        const int j4 = t & (WW / 4 - 1);                  // 0..255
        const int r  = t >> 8;                            // cd*H + i
        const int i  = r & (HH - 1);
        const int cd = r >> 10;                           // c*D + d
        const int d  = cd & (DD - 1);

        const int s0 = s_sh[2 * d];
        const int s1 = s_sh[2 * d + 1];

        const int si = (i - s0) & (HH - 1);
        const float* __restrict__ row = x + ((size_t)cd * HH + si) * WW;

        const int js = ((j4 << 2) - s1) & (WW - 1);

        float4 v;
        if (js <= WW - 4) {
            // Fast path: contiguous 16B read, element-aligned only.
            f4u u = *reinterpret_cast<const f4u*>(row + js);
            v.x = u.x; v.y = u.y; v.z = u.z; v.w = u.w;
        } else {
            // Wrap path: at most 1 lane per wave, and only when s1 % 4 != 0.
            v.x = row[js];
            v.y = row[(js + 1) & (WW - 1)];
            v.z = row[(js + 2) & (WW - 1)];
            v.w = row[(js + 3) & (WW - 1)];
        }

        reinterpret_cast<float4*>(out)[t] = v;
    }
}

extern "C" void kernel_launch(void* const* d_in, const int* in_sizes, int n_in,
                              void* d_out, int out_size, void* d_ws, size_t ws_size,
                              hipStream_t stream) {
    const float* x     = (const float*)d_in[0];
    const int*   shift = (const int*)d_in[1];
    float*       out   = (float*)d_out;

    const int blocks  = 2048;  // 256 CUs x 8 blocks, grid-stride covers the rest
    const int threads = 256;
    PixelShift_kernel<<<blocks, threads, 0, stream>>>(x, shift, out);
}

// Round 4
// 86.762 us; speedup vs baseline: 1.3571x; 1.2275x over previous
//
#include <hip/hip_runtime.h>

// PixelShift: out[c,d,i,j] = x[c,d,(i - s0[d]) & 1023, (j - s1[d]) & 1023]
// C=4, D=16, H=W=1024, float32. Memory-bound circular roll per depth slice.
//
// R3 -> R4: same NT-store theory, but use a clang ext_vector_type for the
// store (HIP's float4 is a struct; __builtin_nontemporal_store rejects it).

#define CC 4
#define DD 16
#define HH 1024
#define WW 1024

typedef float floatx4 __attribute__((ext_vector_type(4)));

// 4-byte-aligned 16B chunk: compiler emits global_load_dwordx4 with align-4
// (gfx950 supports element-misaligned vector access).
struct __align__(4) f4u { float x, y, z, w; };

__global__ __launch_bounds__(256)
void PixelShift_kernel(const float* __restrict__ x,
                       const int* __restrict__ shift,
                       float* __restrict__ out) {
    __shared__ int s_sh[2 * DD];
    if (threadIdx.x < 2 * DD) s_sh[threadIdx.x] = shift[threadIdx.x];
    __syncthreads();

    const int total4 = CC * DD * HH * (WW / 4);           // 16,777,216 float4s
    const int stride = gridDim.x * blockDim.x;
#pragma unroll 4
    for (int t = blockIdx.x * blockDim.x + threadIdx.x; t < total4; t += stride) {
        const int j4 = t & (WW / 4 - 1);                  // 0..255
        const int r  = t >> 8;                            // cd*H + i
        const int i  = r & (HH - 1);
        const int cd = r >> 10;                           // c*D + d
        const int d  = cd & (DD - 1);

        const int s0 = s_sh[2 * d];
        const int s1 = s_sh[2 * d + 1];

        const int si = (i - s0) & (HH - 1);
        const float* __restrict__ row = x + ((size_t)cd * HH + si) * WW;

        const int js = ((j4 << 2) - s1) & (WW - 1);

        floatx4 v;
        if (js <= WW - 4) {
            // Fast path: contiguous 16B read (element-aligned only).
            f4u u = *reinterpret_cast<const f4u*>(row + js);
            v.x = u.x; v.y = u.y; v.z = u.z; v.w = u.w;
        } else {
            // Wrap path: at most 1 lane per wave, only when s1 % 4 != 0.
            v.x = row[js];
            v.y = row[(js + 1) & (WW - 1)];
            v.z = row[(js + 2) & (WW - 1)];
            v.w = row[(js + 3) & (WW - 1)];
        }

        // Nontemporal: output is streaming, never re-read -> don't let it
        // evict x from L2/L3.
        __builtin_nontemporal_store(v, reinterpret_cast<floatx4*>(out) + t);
    }
}

extern "C" void kernel_launch(void* const* d_in, const int* in_sizes, int n_in,
                              void* d_out, int out_size, void* d_ws, size_t ws_size,
                              hipStream_t stream) {
    const float* x     = (const float*)d_in[0];
    const int*   shift = (const int*)d_in[1];
    float*       out   = (float*)d_out;

    const int blocks  = 2048;  // 256 CUs x 8 blocks, grid-stride covers the rest
    const int threads = 256;
    PixelShift_kernel<<<blocks, threads, 0, stream>>>(x, shift, out);
}

// Round 5
// 81.556 us; speedup vs baseline: 1.4438x; 1.0638x over previous
//
#include <hip/hip_runtime.h>

// PixelShift: out[c,d,i,j] = x[c,d,(i - s0[d]) & 1023, (j - s1[d]) & 1023]
// C=4, D=16, H=W=1024, float32. Memory-bound circular roll per depth slice.
//
// R4 -> R5: all global reads 16B-aligned. The sub-float4 misalignment
// (srem = (-s1)&3, wave-uniform) is fixed up in-register: lane loads aligned
// A, gets neighbor's A via __shfl_down (DS pipe, otherwise idle), lane 63
// patches with one aligned load, uniform select reassembles. NT stores keep
// the output stream from evicting x out of L2/L3.

#define CC 4
#define DD 16
#define HH 1024
#define WW 1024

typedef float floatx4 __attribute__((ext_vector_type(4)));

__global__ __launch_bounds__(256)
void PixelShift_kernel(const float* __restrict__ x,
                       const int* __restrict__ shift,
                       float* __restrict__ out) {
    __shared__ int s_sh[2 * DD];
    if (threadIdx.x < 2 * DD) s_sh[threadIdx.x] = shift[threadIdx.x];
    __syncthreads();

    const int lane   = threadIdx.x & 63;
    const int total4 = CC * DD * HH * (WW / 4);           // 16,777,216 float4s
    const int stride = gridDim.x * blockDim.x;
#pragma unroll 2
    for (int t = blockIdx.x * blockDim.x + threadIdx.x; t < total4; t += stride) {
        const int j4 = t & (WW / 4 - 1);                  // 0..255
        const int r  = t >> 8;                            // cd*H + i
        const int i  = r & (HH - 1);
        const int cd = r >> 10;                           // c*D + d
        const int d  = cd & (DD - 1);

        const int s0 = s_sh[2 * d];
        const int s1 = s_sh[2 * d + 1];

        const int si = (i - s0) & (HH - 1);
        const floatx4* __restrict__ row4 =
            reinterpret_cast<const floatx4*>(x + ((size_t)cd * HH + si) * WW);

        const int js   = ((j4 << 2) - s1) & (WW - 1);     // source float offset
        const int a0   = js >> 2;                         // aligned float4 index
        const int srem = js & 3;                          // wave-uniform (= (-s1)&3)

        const floatx4 A = row4[a0];                       // 16B-aligned load
        floatx4 v;
        if (srem == 0) {
            v = A;
        } else {
            // Neighbor lane's A (lane l+1 holds source float4 a0+1).
            floatx4 B;
            B.x = __shfl_down(A.x, 1);
            B.y = __shfl_down(A.y, 1);
            B.z = __shfl_down(A.z, 1);
            B.w = __shfl_down(A.w, 1);
            // Lane 63 has no neighbor in-wave: one aligned patch load
            // (wraps within the row; row base is 16B-aligned).
            if (lane == 63) B = row4[(a0 + 1) & (WW / 4 - 1)];

            if (srem == 1)      v = (floatx4){A.y, A.z, A.w, B.x};
            else if (srem == 2) v = (floatx4){A.z, A.w, B.x, B.y};
            else                v = (floatx4){A.w, B.x, B.y, B.z};
        }

        // Nontemporal: output is streaming, never re-read -> don't evict x.
        __builtin_nontemporal_store(v, reinterpret_cast<floatx4*>(out) + t);
    }
}

extern "C" void kernel_launch(void* const* d_in, const int* in_sizes, int n_in,
                              void* d_out, int out_size, void* d_ws, size_t ws_size,
                              hipStream_t stream) {
    const float* x     = (const float*)d_in[0];
    const int*   shift = (const int*)d_in[1];
    float*       out   = (float*)d_out;

    const int blocks  = 2048;  // 256 CUs x 8 blocks, grid-stride covers the rest
    const int threads = 256;
    PixelShift_kernel<<<blocks, threads, 0, stream>>>(x, shift, out);
}